// Round 2
// baseline (51.731 us; speedup 1.0000x reference)
//
#include <hip/hip_runtime.h>

// FFM layer forward — 2 samples per wave.
// inputs: idx [B,16] int32, w0 [1] f32, w [1048576,1] f32, v [1048576,16,8] f32
// out:    [B,1] f32
//
// Wave handles samples b0, b0+1. Half-wave h (lanes 32h..32h+31) owns sample
// b0+h completely: 16 field-rows of 512 B each, one row per iteration, each of
// the 32 lanes loading one float4 (16 B/lane, fully coalesced). 16 independent
// dwordx4 per wave in flight.
//
// my[lane] = idx[(b0+half)*16 + (c&15)] + (c&15)*PFV   (c = lane&31)
//   - serves the w-gather directly (fields dup'd twice per half; reduce masks 1..8)
//   - serves v-row addresses via __shfl(my, t + 32*half): source lanes 0..15 /
//     32..47 hold fields 0..15 of each half's sample.
//
// After the loop acc[c] = lv quad [4c..4c+3] for this half's sample:
//   flat = 4c+e -> j = c>>1, k = 4*(c&1)+e.
// s[k]: butterfly masks {2,4,8,16}; sq: masks {1,2,4,8,16}; w: masks {1,2,4,8}.
// All reductions stay within the 32-lane half. Lane c==0 of each half writes.

constexpr int F   = 16;
constexpr int PFV = 65536;
constexpr int ROW = 128;  // F*K floats = 512 B

__global__ __launch_bounds__(256) void ffm_fwd2(
    const int* __restrict__ idx, const float* __restrict__ w0,
    const float* __restrict__ w, const float* __restrict__ v,
    float* __restrict__ out, int nB)
{
  const int wid  = (blockIdx.x * 256 + threadIdx.x) >> 6;  // wave id
  const int lane = threadIdx.x & 63;
  const int half = lane >> 5;
  const int c    = lane & 31;

  const int b0 = wid * 2;
  int bs = b0 + half;                 // this half's sample
  if (b0 >= nB) return;
  if (bs >= nB) bs = nB - 1;          // clamp (loads only; store guarded)

  const int f  = c & 15;
  const int my = idx[bs * F + f] + f * PFV;
  const float wv = w[my];

  float4 acc = make_float4(0.f, 0.f, 0.f, 0.f);
#pragma unroll
  for (int t = 0; t < F; ++t) {
    const int r = __shfl(my, t + (half << 5), 64);   // field t of this half's sample
    const float4* row = (const float4*)(v + (size_t)r * ROW);
    const float4 x = row[c];
    acc.x += x.x; acc.y += x.y; acc.z += x.z; acc.w += x.w;
  }

  // sum of squares of lv (this half covers all 128 flats of its sample)
  float q = acc.x * acc.x + acc.y * acc.y + acc.z * acc.z + acc.w * acc.w;

  // s[k] = sum over j (lanes sharing bit0 within the half share a k-quad)
  float4 s = acc;
#pragma unroll
  for (int m = 2; m <= 16; m <<= 1) {
    s.x += __shfl_xor(s.x, m, 64);
    s.y += __shfl_xor(s.y, m, 64);
    s.z += __shfl_xor(s.z, m, 64);
    s.w += __shfl_xor(s.w, m, 64);
  }
  float sp = s.x * s.x + s.y * s.y + s.z * s.z + s.w * s.w;
  sp += __shfl_xor(sp, 1, 64);       // add other k-parity -> sum_k s_k^2

  // q: full reduce within half; wsum: fields are dup'd x2 per half -> masks 1..8
  float wsum = wv;
#pragma unroll
  for (int m = 1; m <= 8; m <<= 1) {
    q    += __shfl_xor(q, m, 64);
    wsum += __shfl_xor(wsum, m, 64);
  }
  q += __shfl_xor(q, 16, 64);

  if (c == 0 && b0 + half < nB)
    out[b0 + half] = w0[0] + wsum + 0.5f * (sp - q);
}

extern "C" void kernel_launch(void* const* d_in, const int* in_sizes, int n_in,
                              void* d_out, int out_size, void* d_ws, size_t ws_size,
                              hipStream_t stream) {
  const int*   idx = (const int*)d_in[0];
  const float* w0  = (const float*)d_in[1];
  const float* w   = (const float*)d_in[2];
  const float* v   = (const float*)d_in[3];
  float*       out = (float*)d_out;

  const int nB = in_sizes[0] / F;                 // 32768
  const int nWaves  = (nB + 1) / 2;               // 2 samples per wave
  const int blocks  = (nWaves + 3) / 4;           // 4 waves per 256-thread block
  ffm_fwd2<<<blocks, 256, 0, stream>>>(idx, w0, w, v, out, nB);
}